// Round 6
// baseline (134.898 us; speedup 1.0000x reference)
//
#include <hip/hip_runtime.h>

// out[b,i,j] = s[b,i] * e[b,j] for 0 <= j - i <= 15, else 0.
// B=8, L=4096, fp32 out (512 MiB) -> pure write-BW-bound.
//
// R5 experiment: two-kernel split.
//   K1: pure zero-fill, structural clone of rocclr fillBufferAligned
//       (grid-stride dwordx4 stores, zero branches/loads) -> should hit
//       the 6.8 TB/s the harness's own fill demonstrates.
//   K2: band patch - one thread per row overwrites its <=16 band elements
//       (2 MiB total, inputs L2-resident, runs after K1 on the stream).

#define BAND 15
#define LDIM 4096

typedef float f32x4 __attribute__((ext_vector_type(4)));

__global__ __launch_bounds__(256) void zero_fill(f32x4* __restrict__ out,
                                                 int n4) {
  int idx = blockIdx.x * blockDim.x + threadIdx.x;
  int stride = gridDim.x * blockDim.x;
  const f32x4 z = {0.f, 0.f, 0.f, 0.f};
  for (int t = idx; t < n4; t += stride) out[t] = z;
}

__global__ __launch_bounds__(256) void band_patch(
    const float* __restrict__ s,
    const float* __restrict__ e,
    float* __restrict__ out) {
  const int tid = blockIdx.x * blockDim.x + threadIdx.x;  // 0 .. 32767 = row
  const int i = tid & (LDIM - 1);
  const int b = tid >> 12;

  const float sv = s[tid];
  const float* __restrict__ eb = e + (b << 12);
  float* __restrict__ orow = out + (size_t)tid * LDIM;

  const int jmax = min(i + BAND, LDIM - 1);
#pragma unroll 4
  for (int j = i; j <= jmax; ++j) orow[j] = sv * eb[j];
}

extern "C" void kernel_launch(void* const* d_in, const int* in_sizes, int n_in,
                              void* d_out, int out_size, void* d_ws, size_t ws_size,
                              hipStream_t stream) {
  const float* s = (const float*)d_in[0];
  const float* e = (const float*)d_in[1];
  float* out = (float*)d_out;

  const int n4 = out_size / 4;  // 33,554,432 float4s
  zero_fill<<<2048, 256, 0, stream>>>(reinterpret_cast<f32x4*>(out), n4);

  const int rows = out_size / LDIM;  // 32768
  band_patch<<<rows / 256, 256, 0, stream>>>(s, e, out);
}

// Round 7
// 101.579 us; speedup vs baseline: 1.3280x; 1.3280x over previous
//
#include <hip/hip_runtime.h>

// out[b,i,j] = s[b,i] * e[b,j] for 0 <= j - i <= 15, else 0.
// B=8, L=4096, fp32 out (512 MiB) -> pure write-BW-bound.
//
// R6: same per-row body as round 3 (best: 98.6us), but fill-shaped launch:
// 2048 persistent blocks, grid-stride over rows, 16 rows per wave.
// Tests whether one-shot block churn (8192 blocks retiring after 16 stores)
// was throttling store issue vs fillBufferAligned's persistent loop.

#define BAND 15
#define LDIM 4096
#define CHUNKS 16   // 4096 floats / (64 lanes * 4 floats/lane)
#define NROWS 32768 // B * L
#define NBLOCKS 2048

typedef float f32x4 __attribute__((ext_vector_type(4)));

__global__ __launch_bounds__(256) void band_outer_rows(
    const float* __restrict__ s,
    const float* __restrict__ e,
    float* __restrict__ out) {
  const int wave = threadIdx.x >> 6;
  const int lane = threadIdx.x & 63;

  for (int row = (blockIdx.x << 2) + wave; row < NROWS; row += NBLOCKS * 4) {
    const int i = row & (LDIM - 1);
    const int b = row >> 12;

    const float sv = s[row];                  // wave-uniform broadcast load
    const float* __restrict__ eb = e + (b << 12);
    f32x4* __restrict__ out4 =
        reinterpret_cast<f32x4*>(out) + (size_t)row * (LDIM / 4) + lane;

    const int c_lo = i >> 8;           // first chunk touching the band
    const int c_hi = (i + BAND) >> 8;  // last chunk touching the band

    const f32x4 z = {0.f, 0.f, 0.f, 0.f};
#pragma unroll
    for (int c = 0; c < CHUNKS; ++c) {
      if (c == c_lo || c == c_hi) {    // wave-uniform scalar branch
        const int j0 = (c << 8) + (lane << 2);
        f32x4 v;
#pragma unroll
        for (int k = 0; k < 4; ++k) {
          const int j = j0 + k;
          v[k] = (j >= i && j - i <= BAND) ? sv * eb[j] : 0.f;
        }
        __builtin_nontemporal_store(v, out4 + c * 64);
      } else {
        __builtin_nontemporal_store(z, out4 + c * 64);
      }
    }
  }
}

extern "C" void kernel_launch(void* const* d_in, const int* in_sizes, int n_in,
                              void* d_out, int out_size, void* d_ws, size_t ws_size,
                              hipStream_t stream) {
  const float* s = (const float*)d_in[0];
  const float* e = (const float*)d_in[1];
  float* out = (float*)d_out;

  band_outer_rows<<<NBLOCKS, 256, 0, stream>>>(s, e, out);
}

// Round 8
// 98.524 us; speedup vs baseline: 1.3692x; 1.0310x over previous
//
#include <hip/hip_runtime.h>

// out[b,i,j] = s[b,i] * e[b,j] for 0 <= j - i <= 15, else 0.
// B=8, L=4096, fp32 out (512 MiB) -> pure write-BW-bound.
//
// FINAL (revert to round-3 best: 98.6 us ~= roofline).
// Model: time = T0 + bytes/BW with T0 ~= 26 us fixed dispatch/ramp cost,
// BW ~= 7.4 TB/s steady write stream — fits both this kernel and the
// harness's own 2 GiB fillBufferAligned (316 us). Four structurally
// different variants (one-shot rows / pipelined loads / plain stores /
// persistent grid-stride) all land 98.6-103.5 us => floor reached.
//
// Structure: one wave (64 lanes) per output row = 16 dwordx4 nontemporal
// stores of 1 KiB each. Row index i is wave-uniform -> the band-chunk test
// is a scalar branch; at most 2 of 16 chunks take the band path (e-loads
// are L1/L2-resident, 128 KiB per input).

#define BAND 15
#define LDIM 4096
#define CHUNKS 16  // 4096 floats / (64 lanes * 4 floats/lane)

typedef float f32x4 __attribute__((ext_vector_type(4)));

__global__ __launch_bounds__(256) void band_outer_rows(
    const float* __restrict__ s,
    const float* __restrict__ e,
    float* __restrict__ out) {
  const int wave = threadIdx.x >> 6;
  const int lane = threadIdx.x & 63;
  const int row  = (blockIdx.x << 2) + wave;  // 0 .. B*L-1 (32768 rows)
  const int i    = row & (LDIM - 1);
  const int b    = row >> 12;

  const float sv = s[row];                    // wave-uniform broadcast load
  const float* __restrict__ eb = e + (b << 12);
  f32x4* __restrict__ out4 =
      reinterpret_cast<f32x4*>(out) + (size_t)row * (LDIM / 4) + lane;

  const int c_lo = i >> 8;            // first chunk touching the band
  const int c_hi = (i + BAND) >> 8;   // last chunk touching the band

  const f32x4 z = {0.f, 0.f, 0.f, 0.f};
#pragma unroll
  for (int c = 0; c < CHUNKS; ++c) {
    if (c == c_lo || c == c_hi) {     // wave-uniform scalar branch
      const int j0 = (c << 8) + (lane << 2);
      f32x4 v;
#pragma unroll
      for (int k = 0; k < 4; ++k) {
        const int j = j0 + k;
        v[k] = (j >= i && j - i <= BAND) ? sv * eb[j] : 0.f;
      }
      __builtin_nontemporal_store(v, out4 + c * 64);
    } else {
      __builtin_nontemporal_store(z, out4 + c * 64);
    }
  }
}

extern "C" void kernel_launch(void* const* d_in, const int* in_sizes, int n_in,
                              void* d_out, int out_size, void* d_ws, size_t ws_size,
                              hipStream_t stream) {
  const float* s = (const float*)d_in[0];
  const float* e = (const float*)d_in[1];
  float* out = (float*)d_out;

  // 8 * 4096 rows, 4 rows (waves) per 256-thread block
  const int rows = out_size / LDIM;   // 32768
  band_outer_rows<<<rows / 4, 256, 0, stream>>>(s, e, out);
}